// Round 1
// baseline (36.760 us; speedup 1.0000x reference)
//
#include <hip/hip_runtime.h>
#include <math.h>

// Rodrigues rotation: R rotates unit(vec1) onto unit(vec2), per (B,N) element.
// B*N = 2,097,152 elements; in: 2 x (elem,3) f32, out: (elem,3,3) f32.
// Memory-bound: ~126 MB total traffic -> target ~20-25 us.

__device__ __forceinline__ void rot_one(float v1x, float v1y, float v1z,
                                        float v2x, float v2y, float v2z,
                                        float* __restrict__ R /* 9 floats */)
{
    const float n1 = sqrtf(v1x * v1x + v1y * v1y + v1z * v1z);
    const float n2 = sqrtf(v2x * v2x + v2y * v2y + v2z * v2z);
    const float ax = v1x / n1, ay = v1y / n1, az = v1z / n1;
    const float bx = v2x / n2, by = v2y / n2, bz = v2z / n2;

    // v = cross(a,b), c = dot(a,b), s = |v|
    const float vx = ay * bz - az * by;
    const float vy = az * bx - ax * bz;
    const float vz = ax * by - ay * bx;
    const float c  = ax * bx + ay * by + az * bz;
    const float s2 = vx * vx + vy * vy + vz * vz;
    const float s  = sqrtf(s2);

    const bool s_zero = (s < 1e-30f);
    const float f = (1.0f - c) / (s_zero ? 1.0f : s2);

    // R = I + K + (v v^T - s^2 I) * f   (K^2 == v v^T - |v|^2 I exactly)
    float r00 = 1.0f + (vx * vx - s2) * f;
    float r01 = -vz  + (vx * vy) * f;
    float r02 =  vy  + (vx * vz) * f;
    float r10 =  vz  + (vy * vx) * f;
    float r11 = 1.0f + (vy * vy - s2) * f;
    float r12 = -vx  + (vy * vz) * f;
    float r20 = -vy  + (vz * vx) * f;
    float r21 =  vx  + (vz * vy) * f;
    float r22 = 1.0f + (vz * vz - s2) * f;

    // 180-degree (antiparallel) branch, computed branchlessly.
    // close = allclose(a, e1) with atol=1e-8, rtol=1e-5 (per component vs |e1|)
    const bool close = (fabsf(ax - 1.0f) <= (1e-8f + 1e-5f)) &&
                       (fabsf(ay) <= 1e-8f) &&
                       (fabsf(az) <= 1e-8f);
    const float exv = close ? 0.0f : 1.0f;   // axis = close ? e2 : e1
    const float eyv = close ? 1.0f : 0.0f;   // (axis.z == 0 always)
    // perp = cross(a, axis)
    float px = -az * eyv;
    float py =  az * exv;
    float pz =  ax * eyv - ay * exv;
    const float pn = sqrtf(px * px + py * py + pz * pz);
    const float pd = (pn == 0.0f) ? 1.0f : pn;
    px /= pd; py /= pd; pz /= pd;
    const float pq = px * px + py * py + pz * pz;
    // R180 = I + 2*(p p^T - |p|^2 I)
    const float q00 = 1.0f + 2.0f * (px * px - pq);
    const float q01 = 2.0f * (px * py);
    const float q02 = 2.0f * (px * pz);
    const float q11 = 1.0f + 2.0f * (py * py - pq);
    const float q12 = 2.0f * (py * pz);
    const float q22 = 1.0f + 2.0f * (pz * pz - pq);

    const bool id_case  = s_zero && (c > 0.0f);
    const bool neg_case = s_zero && (c < 0.0f);

    R[0] = id_case ? 1.0f : (neg_case ? q00 : r00);
    R[1] = id_case ? 0.0f : (neg_case ? q01 : r01);
    R[2] = id_case ? 0.0f : (neg_case ? q02 : r02);
    R[3] = id_case ? 0.0f : (neg_case ? q01 : r10);
    R[4] = id_case ? 1.0f : (neg_case ? q11 : r11);
    R[5] = id_case ? 0.0f : (neg_case ? q12 : r12);
    R[6] = id_case ? 0.0f : (neg_case ? q02 : r20);
    R[7] = id_case ? 0.0f : (neg_case ? q12 : r21);
    R[8] = id_case ? 1.0f : (neg_case ? q22 : r22);
}

// 4 vec3 elements per thread: 3 aligned float4 loads per input, 9 aligned
// float4 stores (144 B contiguous per thread).
__global__ __launch_bounds__(256)
void rodrigues4_kernel(const float4* __restrict__ v1,
                       const float4* __restrict__ v2,
                       float4* __restrict__ out, int n4)
{
    const int t = blockIdx.x * blockDim.x + threadIdx.x;
    if (t >= n4) return;

    const float4 A0 = v1[3 * t + 0], A1 = v1[3 * t + 1], A2 = v1[3 * t + 2];
    const float4 B0 = v2[3 * t + 0], B1 = v2[3 * t + 1], B2 = v2[3 * t + 2];

    const float va[12] = {A0.x, A0.y, A0.z, A0.w, A1.x, A1.y, A1.z, A1.w,
                          A2.x, A2.y, A2.z, A2.w};
    const float vb[12] = {B0.x, B0.y, B0.z, B0.w, B1.x, B1.y, B1.z, B1.w,
                          B2.x, B2.y, B2.z, B2.w};
    float R[36];

#pragma unroll
    for (int e = 0; e < 4; ++e) {
        rot_one(va[3 * e + 0], va[3 * e + 1], va[3 * e + 2],
                vb[3 * e + 0], vb[3 * e + 1], vb[3 * e + 2],
                &R[9 * e]);
    }

    float4* o = out + 9 * (long)t;
#pragma unroll
    for (int k = 0; k < 9; ++k)
        o[k] = make_float4(R[4 * k + 0], R[4 * k + 1], R[4 * k + 2], R[4 * k + 3]);
}

// Scalar tail kernel (n % 4 leftovers; unused for this shape but kept general).
__global__ __launch_bounds__(64)
void rodrigues1_kernel(const float* __restrict__ v1,
                       const float* __restrict__ v2,
                       float* __restrict__ out, int start, int n)
{
    const int i = start + blockIdx.x * blockDim.x + threadIdx.x;
    if (i >= n) return;
    float R[9];
    rot_one(v1[3 * i + 0], v1[3 * i + 1], v1[3 * i + 2],
            v2[3 * i + 0], v2[3 * i + 1], v2[3 * i + 2], R);
#pragma unroll
    for (int k = 0; k < 9; ++k) out[9 * i + k] = R[k];
}

extern "C" void kernel_launch(void* const* d_in, const int* in_sizes, int n_in,
                              void* d_out, int out_size, void* d_ws, size_t ws_size,
                              hipStream_t stream)
{
    const float* v1 = (const float*)d_in[0];
    const float* v2 = (const float*)d_in[1];
    float* out = (float*)d_out;

    const int n  = in_sizes[0] / 3;   // number of vec3 elements (B*N)
    const int n4 = n / 4;

    if (n4 > 0) {
        const int block = 256;
        const int grid = (n4 + block - 1) / block;
        rodrigues4_kernel<<<grid, block, 0, stream>>>(
            (const float4*)v1, (const float4*)v2, (float4*)out, n4);
    }
    const int rem = n - n4 * 4;
    if (rem > 0) {
        rodrigues1_kernel<<<(rem + 63) / 64, 64, 0, stream>>>(
            v1, v2, out, n4 * 4, n);
    }
}

// Round 2
// 24.685 us; speedup vs baseline: 1.4891x; 1.4891x over previous
//
#include <hip/hip_runtime.h>
#include <math.h>

// Rodrigues rotation: R rotates unit(vec1) onto unit(vec2), per (B,N) element.
// B*N = 2,097,152 elements; in: 2 x (elem,3) f32, out: (elem,3,3) f32.
// Memory-bound: ~126 MB total traffic -> floor ~20 us @ 6.3 TB/s.
//
// R1 structure: LDS-staged both directions so every global access is fully
// coalesced per instruction; approx rcp/rsq (1e-7 rel err vs 2e-2 threshold)
// to kill the precise-division VALU sequences.

#define ELEMS_PER_BLOCK 256

__global__ __launch_bounds__(256)
void rodrigues_staged_kernel(const float* __restrict__ v1,
                             const float* __restrict__ v2,
                             float4* __restrict__ out4, int n /* elements */)
{
    __shared__ float lds_a[3 * ELEMS_PER_BLOCK];
    __shared__ float lds_b[3 * ELEMS_PER_BLOCK];
    __shared__ float4 lds_o4[9 * ELEMS_PER_BLOCK / 4];   // 576 float4 = 9216 B
    float* lds_o = (float*)lds_o4;

    const int tid   = threadIdx.x;
    const int base  = blockIdx.x * ELEMS_PER_BLOCK;       // first element
    const long base3 = 3L * base;                         // first float of inputs
    const int nfl   = 3 * n;                              // total input floats

    // ---- cooperative coalesced loads: 3 passes x 256 lanes x 4 B ----
#pragma unroll
    for (int p = 0; p < 3; ++p) {
        const long g = base3 + p * 256 + tid;
        const int  l = p * 256 + tid;
        if (g < nfl) {
            lds_a[l] = v1[g];
            lds_b[l] = v2[g];
        }
    }
    __syncthreads();

    // ---- per-thread compute (element base+tid) ----
    const int e = base + tid;
    if (e < n) {
        const float v1x = lds_a[3 * tid + 0], v1y = lds_a[3 * tid + 1], v1z = lds_a[3 * tid + 2];
        const float v2x = lds_b[3 * tid + 0], v2y = lds_b[3 * tid + 1], v2z = lds_b[3 * tid + 2];

        const float rn1 = __builtin_amdgcn_rsqf(v1x * v1x + v1y * v1y + v1z * v1z);
        const float rn2 = __builtin_amdgcn_rsqf(v2x * v2x + v2y * v2y + v2z * v2z);
        const float ax = v1x * rn1, ay = v1y * rn1, az = v1z * rn1;
        const float bx = v2x * rn2, by = v2y * rn2, bz = v2z * rn2;

        // v = cross(a,b), c = dot(a,b), s2 = |v|^2
        const float vx = ay * bz - az * by;
        const float vy = az * bx - ax * bz;
        const float vz = ax * by - ay * bx;
        const float c  = ax * bx + ay * by + az * bz;
        const float s2 = vx * vx + vy * vy + vz * vz;

        // s < 1e-30  <=>  s2 == 0 in f32 (s2 >= min denormal => s >= ~1e-23)
        const bool s_zero = (s2 == 0.0f);
        const float f = (1.0f - c) * (s_zero ? 1.0f : __builtin_amdgcn_rcpf(s2));

        // R = I + K + (v v^T - s2 I) * f   (K^2 == v v^T - |v|^2 I exactly)
        const float r00 = 1.0f + (vx * vx - s2) * f;
        const float r01 = -vz  + (vx * vy) * f;
        const float r02 =  vy  + (vx * vz) * f;
        const float r10 =  vz  + (vy * vx) * f;
        const float r11 = 1.0f + (vy * vy - s2) * f;
        const float r12 = -vx  + (vy * vz) * f;
        const float r20 = -vy  + (vz * vx) * f;
        const float r21 =  vx  + (vz * vy) * f;
        const float r22 = 1.0f + (vz * vz - s2) * f;

        // 180-degree (antiparallel) branch, branchless.
        const bool close = (fabsf(ax - 1.0f) <= (1e-8f + 1e-5f)) &&
                           (fabsf(ay) <= 1e-8f) &&
                           (fabsf(az) <= 1e-8f);
        const float exv = close ? 0.0f : 1.0f;   // axis = close ? e2 : e1
        const float eyv = close ? 1.0f : 0.0f;
        float px = -az * eyv;
        float py =  az * exv;
        float pz =  ax * eyv - ay * exv;
        const float pq0 = px * px + py * py + pz * pz;
        const float rpn = (pq0 == 0.0f) ? 1.0f : __builtin_amdgcn_rsqf(pq0);
        px *= rpn; py *= rpn; pz *= rpn;
        const float pq = px * px + py * py + pz * pz;
        const float q00 = 1.0f + 2.0f * (px * px - pq);
        const float q01 = 2.0f * (px * py);
        const float q02 = 2.0f * (px * pz);
        const float q11 = 1.0f + 2.0f * (py * py - pq);
        const float q12 = 2.0f * (py * pz);
        const float q22 = 1.0f + 2.0f * (pz * pz - pq);

        const bool id_case  = s_zero && (c > 0.0f);
        const bool neg_case = s_zero && (c < 0.0f);

        float R[9];
        R[0] = id_case ? 1.0f : (neg_case ? q00 : r00);
        R[1] = id_case ? 0.0f : (neg_case ? q01 : r01);
        R[2] = id_case ? 0.0f : (neg_case ? q02 : r02);
        R[3] = id_case ? 0.0f : (neg_case ? q01 : r10);
        R[4] = id_case ? 1.0f : (neg_case ? q11 : r11);
        R[5] = id_case ? 0.0f : (neg_case ? q12 : r12);
        R[6] = id_case ? 0.0f : (neg_case ? q02 : r20);
        R[7] = id_case ? 0.0f : (neg_case ? q12 : r21);
        R[8] = id_case ? 1.0f : (neg_case ? q22 : r22);

        // stride-9 LDS write: 9 odd => 2 lanes/bank over wave64 => free
#pragma unroll
        for (int k = 0; k < 9; ++k) lds_o[9 * tid + k] = R[k];
    }
    __syncthreads();

    // ---- cooperative coalesced stores: float4, 1024 B per wave instr ----
    const long ob4 = 9L * base / 4;                 // block's first float4 in out
    const long n4  = (9L * n) / 4;                  // total float4 in out (divisible here)
#pragma unroll
    for (int p = 0; p < 3; ++p) {
        const int j = p * 256 + tid;                // 0..767, need 576
        if (j < 9 * ELEMS_PER_BLOCK / 4 && ob4 + j < n4)
            out4[ob4 + j] = lds_o4[j];
    }
}

extern "C" void kernel_launch(void* const* d_in, const int* in_sizes, int n_in,
                              void* d_out, int out_size, void* d_ws, size_t ws_size,
                              hipStream_t stream)
{
    const float* v1 = (const float*)d_in[0];
    const float* v2 = (const float*)d_in[1];
    const int n = in_sizes[0] / 3;                  // B*N elements (2,097,152)

    const int grid = (n + ELEMS_PER_BLOCK - 1) / ELEMS_PER_BLOCK;
    rodrigues_staged_kernel<<<grid, 256, 0, stream>>>(
        v1, v2, (float4*)d_out, n);
}

// Round 3
// 24.641 us; speedup vs baseline: 1.4918x; 1.0018x over previous
//
#include <hip/hip_runtime.h>
#include <math.h>

// Rodrigues rotation: R rotates unit(vec1) onto unit(vec2), per (B,N) element.
// B*N = 2,097,152 elements; in: 2 x (elem,3) f32, out: (elem,3,3) f32.
// Memory-bound: ~126 MB total traffic -> floor ~20 us @ 6.3 TB/s copy ceiling.
//
// R2 structure: 4 elements/thread so every memory phase is b128-wide.
//   global->LDS: 3x float4 passes per input (1024 B/wave-instr)
//   LDS->reg:    3x ds_read_b128 per input (stride-3-f4: 8 lanes cover all
//                32 banks -> minimum aliasing, throughput-conflict-free)
//   reg->LDS:    9x ds_write_b128 at stride 9 f4 (same minimal bank pattern)
//   LDS->global: 9x linear coalesced float4 store passes
// LDS aliased (inputs dead after reg read): max(24,36) = 36 KB -> 4 blocks/CU.

#define TPB 256
#define EPT 4
#define EPB (TPB * EPT)          // 1024 elements per block

__device__ __forceinline__ void rot_one(float v1x, float v1y, float v1z,
                                        float v2x, float v2y, float v2z,
                                        float* __restrict__ R /* 9 floats */)
{
    const float rn1 = __builtin_amdgcn_rsqf(v1x * v1x + v1y * v1y + v1z * v1z);
    const float rn2 = __builtin_amdgcn_rsqf(v2x * v2x + v2y * v2y + v2z * v2z);
    const float ax = v1x * rn1, ay = v1y * rn1, az = v1z * rn1;
    const float bx = v2x * rn2, by = v2y * rn2, bz = v2z * rn2;

    // v = cross(a,b), c = dot(a,b), s2 = |v|^2
    const float vx = ay * bz - az * by;
    const float vy = az * bx - ax * bz;
    const float vz = ax * by - ay * bx;
    const float c  = ax * bx + ay * by + az * bz;
    const float s2 = vx * vx + vy * vy + vz * vz;

    // s < 1e-30  <=>  s2 == 0 in f32
    const bool s_zero = (s2 == 0.0f);
    const float f = (1.0f - c) * (s_zero ? 1.0f : __builtin_amdgcn_rcpf(s2));

    // R = I + K + (v v^T - s2 I) * f   (K^2 == v v^T - |v|^2 I exactly)
    const float r00 = 1.0f + (vx * vx - s2) * f;
    const float r01 = -vz  + (vx * vy) * f;
    const float r02 =  vy  + (vx * vz) * f;
    const float r10 =  vz  + (vy * vx) * f;
    const float r11 = 1.0f + (vy * vy - s2) * f;
    const float r12 = -vx  + (vy * vz) * f;
    const float r20 = -vy  + (vz * vx) * f;
    const float r21 =  vx  + (vz * vy) * f;
    const float r22 = 1.0f + (vz * vz - s2) * f;

    // 180-degree (antiparallel) branch, branchless.
    const bool close = (fabsf(ax - 1.0f) <= (1e-8f + 1e-5f)) &&
                       (fabsf(ay) <= 1e-8f) &&
                       (fabsf(az) <= 1e-8f);
    const float exv = close ? 0.0f : 1.0f;   // axis = close ? e2 : e1
    const float eyv = close ? 1.0f : 0.0f;
    float px = -az * eyv;
    float py =  az * exv;
    float pz =  ax * eyv - ay * exv;
    const float pq0 = px * px + py * py + pz * pz;
    const float rpn = (pq0 == 0.0f) ? 1.0f : __builtin_amdgcn_rsqf(pq0);
    px *= rpn; py *= rpn; pz *= rpn;
    const float pq = px * px + py * py + pz * pz;
    const float q00 = 1.0f + 2.0f * (px * px - pq);
    const float q01 = 2.0f * (px * py);
    const float q02 = 2.0f * (px * pz);
    const float q11 = 1.0f + 2.0f * (py * py - pq);
    const float q12 = 2.0f * (py * pz);
    const float q22 = 1.0f + 2.0f * (pz * pz - pq);

    const bool id_case  = s_zero && (c > 0.0f);
    const bool neg_case = s_zero && (c < 0.0f);

    R[0] = id_case ? 1.0f : (neg_case ? q00 : r00);
    R[1] = id_case ? 0.0f : (neg_case ? q01 : r01);
    R[2] = id_case ? 0.0f : (neg_case ? q02 : r02);
    R[3] = id_case ? 0.0f : (neg_case ? q01 : r10);
    R[4] = id_case ? 1.0f : (neg_case ? q11 : r11);
    R[5] = id_case ? 0.0f : (neg_case ? q12 : r12);
    R[6] = id_case ? 0.0f : (neg_case ? q02 : r20);
    R[7] = id_case ? 0.0f : (neg_case ? q12 : r21);
    R[8] = id_case ? 1.0f : (neg_case ? q22 : r22);
}

// Full blocks only: 1024 elements per block, everything b128-wide.
__global__ __launch_bounds__(TPB, 4)
void rodrigues4_staged(const float4* __restrict__ v1,
                       const float4* __restrict__ v2,
                       float4* __restrict__ out)
{
    __shared__ float4 lds[9 * EPB / 4];          // 2304 f4 = 36 KB (aliased)
    float4* in_a = lds;                          // [0..767]
    float4* in_b = lds + (3 * EPB / 4);          // [768..1535]

    const int tid = threadIdx.x;
    const long bi = blockIdx.x;

    // ---- global -> LDS, fully coalesced float4 ----
    const float4* ga = v1 + bi * (3 * EPB / 4);
    const float4* gb = v2 + bi * (3 * EPB / 4);
#pragma unroll
    for (int p = 0; p < 3; ++p) {
        in_a[p * TPB + tid] = ga[p * TPB + tid];
        in_b[p * TPB + tid] = gb[p * TPB + tid];
    }
    __syncthreads();

    // ---- LDS -> regs: 3x ds_read_b128 per input ----
    const float4 A0 = in_a[3 * tid + 0], A1 = in_a[3 * tid + 1], A2 = in_a[3 * tid + 2];
    const float4 B0 = in_b[3 * tid + 0], B1 = in_b[3 * tid + 1], B2 = in_b[3 * tid + 2];
    __syncthreads();                             // inputs dead; reuse LDS for out

    const float va[12] = {A0.x, A0.y, A0.z, A0.w, A1.x, A1.y, A1.z, A1.w,
                          A2.x, A2.y, A2.z, A2.w};
    const float vb[12] = {B0.x, B0.y, B0.z, B0.w, B1.x, B1.y, B1.z, B1.w,
                          B2.x, B2.y, B2.z, B2.w};

    float R[36];
#pragma unroll
    for (int e = 0; e < 4; ++e)
        rot_one(va[3 * e + 0], va[3 * e + 1], va[3 * e + 2],
                vb[3 * e + 0], vb[3 * e + 1], vb[3 * e + 2], &R[9 * e]);

    // ---- regs -> LDS: 9x ds_write_b128 at stride 9 f4 ----
#pragma unroll
    for (int k = 0; k < 9; ++k)
        lds[9 * tid + k] = make_float4(R[4 * k + 0], R[4 * k + 1],
                                       R[4 * k + 2], R[4 * k + 3]);
    __syncthreads();

    // ---- LDS -> global: 9 linear coalesced float4 passes ----
    float4* go = out + bi * (9 * EPB / 4);
#pragma unroll
    for (int p = 0; p < 9; ++p)
        go[p * TPB + tid] = lds[p * TPB + tid];
}

// Scalar tail for n % EPB leftovers (not launched for this shape).
__global__ __launch_bounds__(64)
void rodrigues1_kernel(const float* __restrict__ v1,
                       const float* __restrict__ v2,
                       float* __restrict__ out, int start, int n)
{
    const int i = start + blockIdx.x * blockDim.x + threadIdx.x;
    if (i >= n) return;
    float R[9];
    rot_one(v1[3 * i + 0], v1[3 * i + 1], v1[3 * i + 2],
            v2[3 * i + 0], v2[3 * i + 1], v2[3 * i + 2], R);
#pragma unroll
    for (int k = 0; k < 9; ++k) out[9 * i + k] = R[k];
}

extern "C" void kernel_launch(void* const* d_in, const int* in_sizes, int n_in,
                              void* d_out, int out_size, void* d_ws, size_t ws_size,
                              hipStream_t stream)
{
    const float* v1 = (const float*)d_in[0];
    const float* v2 = (const float*)d_in[1];
    const int n = in_sizes[0] / 3;               // B*N elements (2,097,152)

    const int nfull = n / EPB;                   // full 1024-element blocks
    if (nfull > 0) {
        rodrigues4_staged<<<nfull, TPB, 0, stream>>>(
            (const float4*)v1, (const float4*)v2, (float4*)d_out);
    }
    const int rem = n - nfull * EPB;
    if (rem > 0) {
        rodrigues1_kernel<<<(rem + 63) / 64, 64, 0, stream>>>(
            v1, v2, (float*)d_out, nfull * EPB, n);
    }
}